// Round 19
// baseline (228.165 us; speedup 1.0000x reference)
//
#include <hip/hip_runtime.h>

#define GN 32
#define MT 2048
#define CD 512
#define NSLOT 16
#define NTOKENS 65536
#define SCALE -1.4285714285714286f

typedef float f32x4 __attribute__((ext_vector_type(4)));
typedef float f32x2 __attribute__((ext_vector_type(2)));
typedef int i32x4 __attribute__((ext_vector_type(4)));
typedef int i32x8 __attribute__((ext_vector_type(8)));

// ---- OCP e4m3fn encode/decode: hardware cvt when available, manual fallback ----
__device__ __forceinline__ float fp82f_sw(unsigned b) {
  unsigned s = (b & 0x80u) << 24;
  unsigned em = b & 0x7fu;
  float v;
  if (em >= 8)
    v = __uint_as_float((((em >> 3) + 120u) << 23) | ((em & 7u) << 20));
  else
    v = (float)em * 0x1p-9f;
  return __uint_as_float(__float_as_uint(v) | s);
}

#if __has_builtin(__builtin_amdgcn_cvt_pk_f32_fp8)
template <bool HI>
__device__ __forceinline__ f32x2 fp8dec2(unsigned word) {
  return __builtin_amdgcn_cvt_pk_f32_fp8((int)word, HI);
}
#else
template <bool HI>
__device__ __forceinline__ f32x2 fp8dec2(unsigned word) {
  unsigned w = HI ? (word >> 16) : word;
  f32x2 r;
  r.x = fp82f_sw(w & 0xffu);
  r.y = fp82f_sw((w >> 8) & 0xffu);
  return r;
}
#endif

__device__ __forceinline__ unsigned char f2fp8_sw(float f) {
  unsigned s = (__float_as_uint(f) >> 24) & 0x80u;
  float a = fabsf(f);
  unsigned char r;
  if (a >= 0x1p-6f) {
    int e = (int)(__float_as_uint(a) >> 23) - 127;
    int qi = (int)rintf(__builtin_ldexpf(a, 3 - e));
    if (qi == 16) { qi = 8; ++e; }
    r = (unsigned char)(((e + 7) << 3) | (qi - 8));
  } else {
    r = (unsigned char)(int)rintf(a * 512.0f);
  }
  return (unsigned char)(r | s);
}

#if __has_builtin(__builtin_amdgcn_cvt_pk_fp8_f32)
__device__ __forceinline__ unsigned pk4fp8(float a, float b, float c, float d) {
  int w = __builtin_amdgcn_cvt_pk_fp8_f32(a, b, 0, false);
  w = __builtin_amdgcn_cvt_pk_fp8_f32(c, d, w, true);
  return (unsigned)w;
}
#else
__device__ __forceinline__ unsigned pk4fp8(float a, float b, float c, float d) {
  return (unsigned)f2fp8_sw(a) | ((unsigned)f2fp8_sw(b) << 8) |
         ((unsigned)f2fp8_sw(c) << 16) | ((unsigned)f2fp8_sw(d) << 24);
}
#endif

__device__ __forceinline__ void gload16(const void* g, const void* l) {
  __builtin_amdgcn_global_load_lds((const __attribute__((address_space(1))) unsigned*)g,
                                   (__attribute__((address_space(3))) unsigned*)(
                                       (unsigned long)l),
                                   16, 0, 0);
}

// K1: L2-normalize rows of [NTOKENS,512] fp32 -> fp8 e4m3 for BOTH inputs.
// R11 form — best measured end-to-end total.
__global__ __launch_bounds__(256) void k_norm2(const float* __restrict__ a,
                                               const float* __restrict__ b,
                                               unsigned char* __restrict__ oa,
                                               unsigned char* __restrict__ ob) {
  int wid = threadIdx.x >> 6, lane = threadIdx.x & 63;
  long idx = (long)blockIdx.x * 4 + wid;  // 0..131071
  const float* in = (idx < NTOKENS) ? a : b;
  unsigned char* out = (idx < NTOKENS) ? oa : ob;
  long row = idx & (NTOKENS - 1);
  const float4* src = reinterpret_cast<const float4*>(in + row * CD);
  float4 v0 = src[2 * lane];
  float4 v1 = src[2 * lane + 1];
  float ss = v0.x * v0.x + v0.y * v0.y + v0.z * v0.z + v0.w * v0.w +
             v1.x * v1.x + v1.y * v1.y + v1.z * v1.z + v1.w * v1.w;
#pragma unroll
  for (int off = 32; off; off >>= 1) ss += __shfl_xor(ss, off);
  float rn = 1.0f / fmaxf(sqrtf(ss), 1e-12f);
  uint2 p;
  p.x = pk4fp8(v0.x * rn, v0.y * rn, v0.z * rn, v0.w * rn);
  p.y = pk4fp8(v1.x * rn, v1.y * rn, v1.z * rn, v1.w * rn);
  reinterpret_cast<uint2*>(out + row * CD)[lane] = p;
}

// K2: argmax over slot dim + per-(group,slot) histogram
__global__ __launch_bounds__(256) void k_grp(const float* __restrict__ masks,
                                             int* __restrict__ grp, int* __restrict__ cnt) {
  int t = blockIdx.x * 256 + threadIdx.x;
  int bt = t >> 10, n = t & 1023;
  const float* p = masks + (size_t)bt * NSLOT * 1024 + n;
  float bv = p[0];
  int bs = 0;
#pragma unroll
  for (int s = 1; s < NSLOT; ++s) {
    float v = p[(size_t)s * 1024];
    if (v > bv) { bv = v; bs = s; }
  }
  grp[t] = bs;
  atomicAdd(&cnt[(t >> 11) * NSLOT + bs], 1);
}

// K3a: partial fcsum via LDS-indexed accumulation (proven R8 version, hw decode).
#define FCH 64
#define NCH (MT / FCH)  // 32
__global__ __launch_bounds__(256, 4) void k_fcsum_part(const unsigned char* __restrict__ fc8,
                                                       const int* __restrict__ grp,
                                                       float* __restrict__ part) {
  __shared__ float accs[NSLOT * CD];
  __shared__ int gsh[FCH];
  int g = blockIdx.x >> 5;
  int ch = blockIdx.x & 31;
  int t = threadIdx.x;
  if (t < FCH) gsh[t] = grp[g * MT + ch * FCH + t];
#pragma unroll
  for (int i = 0; i < NSLOT * CD / 256; ++i) accs[i * 256 + t] = 0.f;
  __syncthreads();
  const unsigned char* base = fc8 + ((size_t)g * MT + ch * FCH) * CD + 2 * t;
#pragma unroll 4
  for (int n = 0; n < FCH; ++n) {
    unsigned u = *(const unsigned short*)(base + (size_t)n * CD);
    int gs = gsh[n];
    f32x2 v = fp8dec2<false>(u);
    float* p = &accs[gs * CD + 2 * t];
    p[0] += v.x;
    p[1] += v.y;
  }
  __syncthreads();
  float* dst = part + (size_t)(g * NCH + ch) * (NSLOT * CD);
#pragma unroll
  for (int i = 0; i < NSLOT * CD / 256; ++i) dst[i * 256 + t] = accs[i * 256 + t];
}

// K3b: reduce partials over the 32 chunks
__global__ __launch_bounds__(256) void k_fcsum_red(const float* __restrict__ part,
                                                   float* __restrict__ fcsum) {
  int idx = blockIdx.x * 256 + threadIdx.x;  // < GN*NSLOT*CD = 262144
  int g = idx >> 13;
  int sc = idx & 8191;
  float s = 0.f;
#pragma unroll
  for (int ch = 0; ch < NCH; ++ch)
    s += part[(size_t)(g * NCH + ch) * (NSLOT * CD) + sc];
  fcsum[idx] = s;
}

// K4: MX-fp8 pair kernel at 128x128 tile, 4 waves, 64KB LDS -> 2 blocks/CU.
// Same proven depth-1 schedule/swizzle as the 256^2 R9 version; the smaller
// tile restores cross-block overlap (m114): while one block sits in its
// vmcnt-drain barrier, the co-resident block's waves issue MFMAs.
// Guide data point: 128^2 beats 256^2 for simple 2-barrier loops (m103).
#define BM 128
#define BN 128
#define BKB 128
#define NTILE 64  // 16 col-tiles x 4 k-tiles

__global__ __launch_bounds__(256, 2) void k_pair(const unsigned char* __restrict__ ft8,
                                                 const unsigned char* __restrict__ fc8,
                                                 float* __restrict__ sexp_out) {
  extern __shared__ char smem[];  // A0[16K] A1[16K] B0[16K] B1[16K]

  const int b = blockIdx.x;            // 512 blocks
  const int xcd = b & 7;
  const int slot = b >> 3;             // 0..63
  const int g = (slot >> 4) * 8 + xcd; // 4 groups per XCD
  const int rt = slot & 15;            // 16 row tiles
  const int r0 = rt * BM;

  const int tid = threadIdx.x;
  const int lane = tid & 63;
  const int wid = tid >> 6;  // 0..3
  const int wr = wid >> 1;   // 0..1
  const int wc = wid & 1;    // 0..1
  const int frow = lane & 15;
  const int l4 = lane >> 4;  // 0..3 -> k-block l4*32 bytes
  const int f7 = frow & 7;

  const unsigned char* Abase = ft8 + (size_t)g * MT * CD;
  const unsigned char* Bbase = fc8 + (size_t)g * MT * CD;

  const int lrow = lane >> 3;                  // 0..7
  const int koff = ((lane & 7) ^ lrow) << 4;   // pre-swizzled source chunk (bytes)

  const int c0off = ((2 * l4) ^ f7) << 4;
  const int c1off = ((2 * l4 + 1) ^ f7) << 4;
  const int baseA = (wr * 64 + frow) * 128;
  const int baseB = (wc * 64 + frow) * 128;

  f32x4 acc[4][4];
#pragma unroll
  for (int m = 0; m < 4; ++m)
#pragma unroll
    for (int n = 0; n < 4; ++n) acc[m][n] = (f32x4){0.f, 0.f, 0.f, 0.f};
  float sexp_loc[4][4];
#pragma unroll
  for (int m = 0; m < 4; ++m)
#pragma unroll
    for (int r = 0; r < 4; ++r) sexp_loc[m][r] = 0.f;

#define STAGE(TT, PB)                                                         \
  {                                                                           \
    const int kk_ = ((TT) & 3) * BKB;                                         \
    const int n0_ = ((TT) >> 2) * BN;                                         \
    char* dA_ = smem + (size_t)(PB)*16384;                                    \
    char* dB_ = smem + 32768 + (size_t)(PB)*16384;                            \
    _Pragma("unroll") for (int j_ = 0; j_ < 4; ++j_) {                        \
      const int rb_ = wid * 32 + j_ * 8;                                      \
      gload16(Abase + (size_t)(r0 + rb_ + lrow) * CD + kk_ + koff,            \
              dA_ + (size_t)rb_ * BKB);                                       \
      gload16(Bbase + (size_t)(n0_ + rb_ + lrow) * CD + kk_ + koff,           \
              dB_ + (size_t)rb_ * BKB);                                       \
    }                                                                         \
  }

  STAGE(0, 0)
  __syncthreads();

  int pb = 0;
  for (int t = 0; t < NTILE; ++t) {
    if (t + 1 < NTILE) STAGE(t + 1, pb ^ 1)

    const char* cA = smem + (size_t)pb * 16384;
    const char* cB = smem + 32768 + (size_t)pb * 16384;
    __builtin_amdgcn_s_setprio(1);
    i32x8 bfv[4];
#pragma unroll
    for (int n = 0; n < 4; ++n) {
      i32x4 lo = *(const i32x4*)(cB + baseB + n * 2048 + c0off);
      i32x4 hi = *(const i32x4*)(cB + baseB + n * 2048 + c1off);
      bfv[n] = __builtin_shufflevector(lo, hi, 0, 1, 2, 3, 4, 5, 6, 7);
    }
#pragma unroll
    for (int m = 0; m < 4; ++m) {
      i32x4 lo = *(const i32x4*)(cA + baseA + m * 2048 + c0off);
      i32x4 hi = *(const i32x4*)(cA + baseA + m * 2048 + c1off);
      i32x8 af = __builtin_shufflevector(lo, hi, 0, 1, 2, 3, 4, 5, 6, 7);
#pragma unroll
      for (int n = 0; n < 4; ++n)
        acc[m][n] = __builtin_amdgcn_mfma_scale_f32_16x16x128_f8f6f4(
            af, bfv[n], acc[m][n], 0, 0, 0, 0x7f7f7f7f, 0, 0x7f7f7f7f);
    }
    __builtin_amdgcn_s_setprio(0);

    // col-tile complete every 4 tiles -> exp-accumulate (logits bounded ~10.2)
    if ((t & 3) == 3) {
#pragma unroll
      for (int m = 0; m < 4; ++m)
#pragma unroll
        for (int r = 0; r < 4; ++r) {
          float e = 0.f;
#pragma unroll
          for (int n = 0; n < 4; ++n) e += exp2f(acc[m][n][r] * 14.4269504089f);
          sexp_loc[m][r] += e;
        }
#pragma unroll
      for (int m = 0; m < 4; ++m)
#pragma unroll
        for (int n = 0; n < 4; ++n) acc[m][n] = (f32x4){0.f, 0.f, 0.f, 0.f};
    }

    __syncthreads();  // drains gloads + all waves done with buf[pb]
    pb ^= 1;
  }
#undef STAGE

  // reduce over the 16 column-lanes (C/D: col=lane&15, row=(lane>>4)*4+reg)
#pragma unroll
  for (int m = 0; m < 4; ++m)
#pragma unroll
    for (int r = 0; r < 4; ++r) {
      float v = sexp_loc[m][r];
      v += __shfl_xor(v, 1);
      v += __shfl_xor(v, 2);
      v += __shfl_xor(v, 4);
      v += __shfl_xor(v, 8);
      sexp_loc[m][r] = v;
    }
  __syncthreads();
  float* scr = (float*)smem;  // [4 waves][64 rows]
  if (frow == 0) {
#pragma unroll
    for (int m = 0; m < 4; ++m)
#pragma unroll
      for (int r = 0; r < 4; ++r) scr[wid * 64 + m * 16 + l4 * 4 + r] = sexp_loc[m][r];
  }
  __syncthreads();
  if (tid < BM) {
    int wrr = tid >> 6, rl = tid & 63;  // wave rows: wid = wrr*2 + wc
    float s = scr[(wrr * 2 + 0) * 64 + rl] + scr[(wrr * 2 + 1) * 64 + rl];
    sexp_out[(size_t)g * MT + r0 + tid] = s;
  }
}

// K5: per-token loss fused with final mean (fp8 inputs, hw decode)
__global__ __launch_bounds__(256) void k_loss(const unsigned char* __restrict__ ft8,
                                              const unsigned char* __restrict__ fc8,
                                              const float* __restrict__ fcsum,
                                              const int* __restrict__ grp,
                                              const int* __restrict__ cnt,
                                              const float* __restrict__ sexp,
                                              float* __restrict__ out) {
  __shared__ float sh[4];
  int wid = threadIdx.x >> 6, lane = threadIdx.x & 63;
  float wsum = 0.f;
  for (int t = blockIdx.x * 4 + wid; t < NTOKENS; t += 4096) {
    int g = t >> 11;
    uint2 u1 = reinterpret_cast<const uint2*>(ft8 + (size_t)t * CD)[lane];
    uint2 u2 = reinterpret_cast<const uint2*>(fc8 + (size_t)t * CD)[lane];
    int gs = grp[t];
    const float4* srv = (const float4*)(fcsum + ((size_t)g * NSLOT + gs) * CD);
    float4 s0 = srv[2 * lane];
    float4 s1 = srv[2 * lane + 1];
    f32x2 a01 = fp8dec2<false>(u1.x), a23 = fp8dec2<true>(u1.x);
    f32x2 a45 = fp8dec2<false>(u1.y), a67 = fp8dec2<true>(u1.y);
    f32x2 c01 = fp8dec2<false>(u2.x), c23 = fp8dec2<true>(u2.x);
    f32x2 c45 = fp8dec2<false>(u2.y), c67 = fp8dec2<true>(u2.y);
    float d1 = a01.x * c01.x + a01.y * c01.y + a23.x * c23.x + a23.y * c23.y +
               a45.x * c45.x + a45.y * c45.y + a67.x * c67.x + a67.y * c67.y;
    float d2 = a01.x * s0.x + a01.y * s0.y + a23.x * s0.z + a23.y * s0.w +
               a45.x * s1.x + a45.y * s1.y + a67.x * s1.z + a67.y * s1.w;
#pragma unroll
    for (int off = 32; off; off >>= 1) {
      d1 += __shfl_xor(d1, off);
      d2 += __shfl_xor(d2, off);
    }
    if (lane == 0) {
      float lse = __logf(sexp[t]);
      float cm = (float)cnt[g * NSLOT + gs];
      wsum += 0.5f * SCALE * (d2 * 10.0f / cm + d1 * 10.0f - 2.0f * lse);
    }
  }
  if (lane == 0) sh[wid] = wsum;
  __syncthreads();
  if (threadIdx.x == 0)
    atomicAdd(out, (sh[0] + sh[1] + sh[2] + sh[3]) * (1.0f / NTOKENS));
}

extern "C" void kernel_launch(void* const* d_in, const int* in_sizes, int n_in,
                              void* d_out, int out_size, void* d_ws, size_t ws_size,
                              hipStream_t stream) {
  const float* ft = (const float*)d_in[0];
  const float* fc = (const float*)d_in[1];
  const float* masks = (const float*)d_in[2];
  char* ws = (char*)d_ws;

  unsigned char* ft8 = (unsigned char*)(ws);                 // 33554432
  unsigned char* fc8 = (unsigned char*)(ws + 33554432);      // 33554432
  int* grp = (int*)(ws + 67108864);                          // 262144
  int* cnt = (int*)(ws + 67371008);                          // 2048
  float* fcsum = (float*)(ws + 67373056);                    // 1048576
  float* sexp = (float*)(ws + 68421632);                     // 262144
  float* part = (float*)(ws + 68683776);                     // 33554432
  float* out = (float*)d_out;

  static int lds_attr_set = 0;
  if (!lds_attr_set) {
    (void)hipFuncSetAttribute((const void*)k_pair,
                              hipFuncAttributeMaxDynamicSharedMemorySize, 65536);
    lds_attr_set = 1;
  }

  (void)hipMemsetAsync(cnt, 0, GN * NSLOT * sizeof(int), stream);
  (void)hipMemsetAsync(out, 0, sizeof(float), stream);
  k_norm2<<<NTOKENS / 2, 256, 0, stream>>>(ft, fc, ft8, fc8);
  k_grp<<<NTOKENS / 256, 256, 0, stream>>>(masks, grp, cnt);
  k_fcsum_part<<<GN * NCH, 256, 0, stream>>>(fc8, grp, part);
  k_fcsum_red<<<GN * NSLOT * CD / 256, 256, 0, stream>>>(part, fcsum);
  k_pair<<<GN * (MT / BM), 256, 65536, stream>>>(ft8, fc8, sexp);
  k_loss<<<1024, 256, 0, stream>>>(ft8, fc8, fcsum, grp, cnt, sexp, out);
}

// Round 20
// 221.862 us; speedup vs baseline: 1.0284x; 1.0284x over previous
//
#include <hip/hip_runtime.h>

#define GN 32
#define MT 2048
#define CD 512
#define NSLOT 16
#define NTOKENS 65536
#define SCALE -1.4285714285714286f

typedef float f32x4 __attribute__((ext_vector_type(4)));
typedef float f32x2 __attribute__((ext_vector_type(2)));
typedef int i32x4 __attribute__((ext_vector_type(4)));
typedef int i32x8 __attribute__((ext_vector_type(8)));

// ---- OCP e4m3fn encode/decode: hardware cvt when available, manual fallback ----
__device__ __forceinline__ float fp82f_sw(unsigned b) {
  unsigned s = (b & 0x80u) << 24;
  unsigned em = b & 0x7fu;
  float v;
  if (em >= 8)
    v = __uint_as_float((((em >> 3) + 120u) << 23) | ((em & 7u) << 20));
  else
    v = (float)em * 0x1p-9f;
  return __uint_as_float(__float_as_uint(v) | s);
}

#if __has_builtin(__builtin_amdgcn_cvt_pk_f32_fp8)
template <bool HI>
__device__ __forceinline__ f32x2 fp8dec2(unsigned word) {
  return __builtin_amdgcn_cvt_pk_f32_fp8((int)word, HI);
}
#else
template <bool HI>
__device__ __forceinline__ f32x2 fp8dec2(unsigned word) {
  unsigned w = HI ? (word >> 16) : word;
  f32x2 r;
  r.x = fp82f_sw(w & 0xffu);
  r.y = fp82f_sw((w >> 8) & 0xffu);
  return r;
}
#endif

__device__ __forceinline__ unsigned char f2fp8_sw(float f) {
  unsigned s = (__float_as_uint(f) >> 24) & 0x80u;
  float a = fabsf(f);
  unsigned char r;
  if (a >= 0x1p-6f) {
    int e = (int)(__float_as_uint(a) >> 23) - 127;
    int qi = (int)rintf(__builtin_ldexpf(a, 3 - e));
    if (qi == 16) { qi = 8; ++e; }
    r = (unsigned char)(((e + 7) << 3) | (qi - 8));
  } else {
    r = (unsigned char)(int)rintf(a * 512.0f);
  }
  return (unsigned char)(r | s);
}

#if __has_builtin(__builtin_amdgcn_cvt_pk_fp8_f32)
__device__ __forceinline__ unsigned pk4fp8(float a, float b, float c, float d) {
  int w = __builtin_amdgcn_cvt_pk_fp8_f32(a, b, 0, false);
  w = __builtin_amdgcn_cvt_pk_fp8_f32(c, d, w, true);
  return (unsigned)w;
}
#else
__device__ __forceinline__ unsigned pk4fp8(float a, float b, float c, float d) {
  return (unsigned)f2fp8_sw(a) | ((unsigned)f2fp8_sw(b) << 8) |
         ((unsigned)f2fp8_sw(c) << 16) | ((unsigned)f2fp8_sw(d) << 24);
}
#endif

__device__ __forceinline__ void gload16(const void* g, const void* l) {
  __builtin_amdgcn_global_load_lds((const __attribute__((address_space(1))) unsigned*)g,
                                   (__attribute__((address_space(3))) unsigned*)(
                                       (unsigned long)l),
                                   16, 0, 0);
}

// K1: L2-normalize rows of [NTOKENS,512] fp32 -> fp8 e4m3 for BOTH inputs.
// R11 form — best measured end-to-end total (221.8 us config).
__global__ __launch_bounds__(256) void k_norm2(const float* __restrict__ a,
                                               const float* __restrict__ b,
                                               unsigned char* __restrict__ oa,
                                               unsigned char* __restrict__ ob) {
  int wid = threadIdx.x >> 6, lane = threadIdx.x & 63;
  long idx = (long)blockIdx.x * 4 + wid;  // 0..131071
  const float* in = (idx < NTOKENS) ? a : b;
  unsigned char* out = (idx < NTOKENS) ? oa : ob;
  long row = idx & (NTOKENS - 1);
  const float4* src = reinterpret_cast<const float4*>(in + row * CD);
  float4 v0 = src[2 * lane];
  float4 v1 = src[2 * lane + 1];
  float ss = v0.x * v0.x + v0.y * v0.y + v0.z * v0.z + v0.w * v0.w +
             v1.x * v1.x + v1.y * v1.y + v1.z * v1.z + v1.w * v1.w;
#pragma unroll
  for (int off = 32; off; off >>= 1) ss += __shfl_xor(ss, off);
  float rn = 1.0f / fmaxf(sqrtf(ss), 1e-12f);
  uint2 p;
  p.x = pk4fp8(v0.x * rn, v0.y * rn, v0.z * rn, v0.w * rn);
  p.y = pk4fp8(v1.x * rn, v1.y * rn, v1.z * rn, v1.w * rn);
  reinterpret_cast<uint2*>(out + row * CD)[lane] = p;
}

// K2: argmax over slot dim + per-(group,slot) histogram
__global__ __launch_bounds__(256) void k_grp(const float* __restrict__ masks,
                                             int* __restrict__ grp, int* __restrict__ cnt) {
  int t = blockIdx.x * 256 + threadIdx.x;
  int bt = t >> 10, n = t & 1023;
  const float* p = masks + (size_t)bt * NSLOT * 1024 + n;
  float bv = p[0];
  int bs = 0;
#pragma unroll
  for (int s = 1; s < NSLOT; ++s) {
    float v = p[(size_t)s * 1024];
    if (v > bv) { bv = v; bs = s; }
  }
  grp[t] = bs;
  atomicAdd(&cnt[(t >> 11) * NSLOT + bs], 1);
}

// K3a: partial fcsum via LDS-indexed accumulation (proven R8 version, hw decode).
#define FCH 64
#define NCH (MT / FCH)  // 32
__global__ __launch_bounds__(256, 4) void k_fcsum_part(const unsigned char* __restrict__ fc8,
                                                       const int* __restrict__ grp,
                                                       float* __restrict__ part) {
  __shared__ float accs[NSLOT * CD];
  __shared__ int gsh[FCH];
  int g = blockIdx.x >> 5;
  int ch = blockIdx.x & 31;
  int t = threadIdx.x;
  if (t < FCH) gsh[t] = grp[g * MT + ch * FCH + t];
#pragma unroll
  for (int i = 0; i < NSLOT * CD / 256; ++i) accs[i * 256 + t] = 0.f;
  __syncthreads();
  const unsigned char* base = fc8 + ((size_t)g * MT + ch * FCH) * CD + 2 * t;
#pragma unroll 4
  for (int n = 0; n < FCH; ++n) {
    unsigned u = *(const unsigned short*)(base + (size_t)n * CD);
    int gs = gsh[n];
    f32x2 v = fp8dec2<false>(u);
    float* p = &accs[gs * CD + 2 * t];
    p[0] += v.x;
    p[1] += v.y;
  }
  __syncthreads();
  float* dst = part + (size_t)(g * NCH + ch) * (NSLOT * CD);
#pragma unroll
  for (int i = 0; i < NSLOT * CD / 256; ++i) dst[i * 256 + t] = accs[i * 256 + t];
}

// K3b: reduce partials over the 32 chunks
__global__ __launch_bounds__(256) void k_fcsum_red(const float* __restrict__ part,
                                                   float* __restrict__ fcsum) {
  int idx = blockIdx.x * 256 + threadIdx.x;  // < GN*NSLOT*CD = 262144
  int g = idx >> 13;
  int sc = idx & 8191;
  float s = 0.f;
#pragma unroll
  for (int ch = 0; ch < NCH; ++ch)
    s += part[(size_t)(g * NCH + ch) * (NSLOT * CD) + sc];
  fcsum[idx] = s;
}

// K4: MX-fp8 256x256-tile pair kernel — exact R9 structure (98.7 us proven).
// Schedule frozen at depth-1: depth-2 spills (R6/R15); 128^2 tile neutral-worse
// (R19: MfmaUtil unchanged -> VALU/LDS-issue co-bound, not drain-bound).
#define BM 256
#define BN 256
#define BKB 128
#define NTILE 32  // 8 col-tiles x 4 k-tiles

__global__ __launch_bounds__(512, 2) void k_pair(const unsigned char* __restrict__ ft8,
                                                 const unsigned char* __restrict__ fc8,
                                                 float* __restrict__ sexp_out) {
  extern __shared__ char smem[];  // A0[32K] A1[32K] B0[32K] B1[32K]

  const int b = blockIdx.x;
  const int xcd = b & 7;
  const int slot = b >> 3;
  const int g = (slot >> 3) * 8 + xcd;
  const int rt = slot & 7;
  const int r0 = rt * BM;

  const int tid = threadIdx.x;
  const int lane = tid & 63;
  const int wid = tid >> 6;
  const int wr = wid >> 2;   // 0..1
  const int wc = wid & 3;    // 0..3
  const int frow = lane & 15;
  const int l4 = lane >> 4;  // 0..3 -> k-block l4*32 bytes
  const int f7 = frow & 7;

  const unsigned char* Abase = ft8 + (size_t)g * MT * CD;
  const unsigned char* Bbase = fc8 + (size_t)g * MT * CD;

  const int lrow = lane >> 3;                  // 0..7
  const int koff = ((lane & 7) ^ lrow) << 4;   // pre-swizzled source chunk (bytes)

  const int c0off = ((2 * l4) ^ f7) << 4;
  const int c1off = ((2 * l4 + 1) ^ f7) << 4;
  const int baseA = (wr * 128 + frow) * 128;
  const int baseB = (wc * 64 + frow) * 128;

  f32x4 acc[8][4];
#pragma unroll
  for (int m = 0; m < 8; ++m)
#pragma unroll
    for (int n = 0; n < 4; ++n) acc[m][n] = (f32x4){0.f, 0.f, 0.f, 0.f};
  float sexp_loc[8][4];
#pragma unroll
  for (int m = 0; m < 8; ++m)
#pragma unroll
    for (int r = 0; r < 4; ++r) sexp_loc[m][r] = 0.f;

#define STAGE(TT, PB)                                                         \
  {                                                                           \
    const int kk_ = ((TT) & 3) * BKB;                                         \
    const int n0_ = ((TT) >> 2) * BN;                                         \
    char* dA_ = smem + (size_t)(PB)*32768;                                    \
    char* dB_ = smem + 65536 + (size_t)(PB)*32768;                            \
    _Pragma("unroll") for (int j_ = 0; j_ < 4; ++j_) {                        \
      const int rb_ = wid * 32 + j_ * 8;                                      \
      gload16(Abase + (size_t)(r0 + rb_ + lrow) * CD + kk_ + koff,            \
              dA_ + (size_t)rb_ * BKB);                                       \
      gload16(Bbase + (size_t)(n0_ + rb_ + lrow) * CD + kk_ + koff,           \
              dB_ + (size_t)rb_ * BKB);                                       \
    }                                                                         \
  }

  STAGE(0, 0)
  __syncthreads();

  int pb = 0;
  for (int t = 0; t < NTILE; ++t) {
    if (t + 1 < NTILE) STAGE(t + 1, pb ^ 1)

    const char* cA = smem + (size_t)pb * 32768;
    const char* cB = smem + 65536 + (size_t)pb * 32768;
    __builtin_amdgcn_s_setprio(1);
    i32x8 bfv[4];
#pragma unroll
    for (int n = 0; n < 4; ++n) {
      i32x4 lo = *(const i32x4*)(cB + baseB + n * 2048 + c0off);
      i32x4 hi = *(const i32x4*)(cB + baseB + n * 2048 + c1off);
      bfv[n] = __builtin_shufflevector(lo, hi, 0, 1, 2, 3, 4, 5, 6, 7);
    }
#pragma unroll
    for (int m = 0; m < 8; ++m) {
      i32x4 lo = *(const i32x4*)(cA + baseA + m * 2048 + c0off);
      i32x4 hi = *(const i32x4*)(cA + baseA + m * 2048 + c1off);
      i32x8 af = __builtin_shufflevector(lo, hi, 0, 1, 2, 3, 4, 5, 6, 7);
#pragma unroll
      for (int n = 0; n < 4; ++n)
        acc[m][n] = __builtin_amdgcn_mfma_scale_f32_16x16x128_f8f6f4(
            af, bfv[n], acc[m][n], 0, 0, 0, 0x7f7f7f7f, 0, 0x7f7f7f7f);
    }
    __builtin_amdgcn_s_setprio(0);

    if ((t & 3) == 3) {
#pragma unroll
      for (int m = 0; m < 8; ++m)
#pragma unroll
        for (int r = 0; r < 4; ++r) {
          float e = 0.f;
#pragma unroll
          for (int n = 0; n < 4; ++n) e += exp2f(acc[m][n][r] * 14.4269504089f);
          sexp_loc[m][r] += e;
        }
#pragma unroll
      for (int m = 0; m < 8; ++m)
#pragma unroll
        for (int n = 0; n < 4; ++n) acc[m][n] = (f32x4){0.f, 0.f, 0.f, 0.f};
    }

    __syncthreads();
    pb ^= 1;
  }
#undef STAGE

#pragma unroll
  for (int m = 0; m < 8; ++m)
#pragma unroll
    for (int r = 0; r < 4; ++r) {
      float v = sexp_loc[m][r];
      v += __shfl_xor(v, 1);
      v += __shfl_xor(v, 2);
      v += __shfl_xor(v, 4);
      v += __shfl_xor(v, 8);
      sexp_loc[m][r] = v;
    }
  __syncthreads();
  float* scr = (float*)smem;  // [8 waves][128 rows]
  if (frow == 0) {
#pragma unroll
    for (int m = 0; m < 8; ++m)
#pragma unroll
      for (int r = 0; r < 4; ++r) scr[wid * 128 + m * 16 + l4 * 4 + r] = sexp_loc[m][r];
  }
  __syncthreads();
  if (tid < 256) {
    int wrr = tid >> 7, rl = tid & 127;
    float s = scr[(wrr * 4 + 0) * 128 + rl] + scr[(wrr * 4 + 1) * 128 + rl] +
              scr[(wrr * 4 + 2) * 128 + rl] + scr[(wrr * 4 + 3) * 128 + rl];
    sexp_out[(size_t)g * MT + r0 + tid] = s;
  }
}

// K5: per-token loss fused with final mean (fp8 inputs, hw decode)
__global__ __launch_bounds__(256) void k_loss(const unsigned char* __restrict__ ft8,
                                              const unsigned char* __restrict__ fc8,
                                              const float* __restrict__ fcsum,
                                              const int* __restrict__ grp,
                                              const int* __restrict__ cnt,
                                              const float* __restrict__ sexp,
                                              float* __restrict__ out) {
  __shared__ float sh[4];
  int wid = threadIdx.x >> 6, lane = threadIdx.x & 63;
  float wsum = 0.f;
  for (int t = blockIdx.x * 4 + wid; t < NTOKENS; t += 4096) {
    int g = t >> 11;
    uint2 u1 = reinterpret_cast<const uint2*>(ft8 + (size_t)t * CD)[lane];
    uint2 u2 = reinterpret_cast<const uint2*>(fc8 + (size_t)t * CD)[lane];
    int gs = grp[t];
    const float4* srv = (const float4*)(fcsum + ((size_t)g * NSLOT + gs) * CD);
    float4 s0 = srv[2 * lane];
    float4 s1 = srv[2 * lane + 1];
    f32x2 a01 = fp8dec2<false>(u1.x), a23 = fp8dec2<true>(u1.x);
    f32x2 a45 = fp8dec2<false>(u1.y), a67 = fp8dec2<true>(u1.y);
    f32x2 c01 = fp8dec2<false>(u2.x), c23 = fp8dec2<true>(u2.x);
    f32x2 c45 = fp8dec2<false>(u2.y), c67 = fp8dec2<true>(u2.y);
    float d1 = a01.x * c01.x + a01.y * c01.y + a23.x * c23.x + a23.y * c23.y +
               a45.x * c45.x + a45.y * c45.y + a67.x * c67.x + a67.y * c67.y;
    float d2 = a01.x * s0.x + a01.y * s0.y + a23.x * s0.z + a23.y * s0.w +
               a45.x * s1.x + a45.y * s1.y + a67.x * s1.z + a67.y * s1.w;
#pragma unroll
    for (int off = 32; off; off >>= 1) {
      d1 += __shfl_xor(d1, off);
      d2 += __shfl_xor(d2, off);
    }
    if (lane == 0) {
      float lse = __logf(sexp[t]);
      float cm = (float)cnt[g * NSLOT + gs];
      wsum += 0.5f * SCALE * (d2 * 10.0f / cm + d1 * 10.0f - 2.0f * lse);
    }
  }
  if (lane == 0) sh[wid] = wsum;
  __syncthreads();
  if (threadIdx.x == 0)
    atomicAdd(out, (sh[0] + sh[1] + sh[2] + sh[3]) * (1.0f / NTOKENS));
}

extern "C" void kernel_launch(void* const* d_in, const int* in_sizes, int n_in,
                              void* d_out, int out_size, void* d_ws, size_t ws_size,
                              hipStream_t stream) {
  const float* ft = (const float*)d_in[0];
  const float* fc = (const float*)d_in[1];
  const float* masks = (const float*)d_in[2];
  char* ws = (char*)d_ws;

  unsigned char* ft8 = (unsigned char*)(ws);                 // 33554432
  unsigned char* fc8 = (unsigned char*)(ws + 33554432);      // 33554432
  int* grp = (int*)(ws + 67108864);                          // 262144
  int* cnt = (int*)(ws + 67371008);                          // 2048
  float* fcsum = (float*)(ws + 67373056);                    // 1048576
  float* sexp = (float*)(ws + 68421632);                     // 262144
  float* part = (float*)(ws + 68683776);                     // 33554432
  float* out = (float*)d_out;

  static int lds_attr_set = 0;
  if (!lds_attr_set) {
    (void)hipFuncSetAttribute((const void*)k_pair,
                              hipFuncAttributeMaxDynamicSharedMemorySize, 131072);
    lds_attr_set = 1;
  }

  (void)hipMemsetAsync(cnt, 0, GN * NSLOT * sizeof(int), stream);
  (void)hipMemsetAsync(out, 0, sizeof(float), stream);
  k_norm2<<<NTOKENS / 2, 256, 0, stream>>>(ft, fc, ft8, fc8);
  k_grp<<<NTOKENS / 256, 256, 0, stream>>>(masks, grp, cnt);
  k_fcsum_part<<<GN * NCH, 256, 0, stream>>>(fc8, grp, part);
  k_fcsum_red<<<GN * NSLOT * CD / 256, 256, 0, stream>>>(part, fcsum);
  k_pair<<<GN * (MT / BM), 512, 131072, stream>>>(ft8, fc8, sexp);
  k_loss<<<1024, 256, 0, stream>>>(ft8, fc8, fcsum, grp, cnt, sexp, out);
}